// Round 1
// baseline (678.714 us; speedup 1.0000x reference)
//
#include <hip/hip_runtime.h>

// BlockDiagonalAggregator: out[b,:] = sum_k softmax_k(<keys[sigma[b,k]], h[b,k,:]>) * h[b,k,:]
// B=4096, K=64, D=512, N_AGENTS=64 (sigma==64 -> unassigned -> logit=-1e9)
//
// One block (512 threads = 8 waves) per batch row b. h[b] (128 KiB) is read
// from HBM exactly ONCE and cached in registers (64 f32/thread): thread
// (wave w, lane l) owns dims [l*8, l*8+8) of k-rows {8w..8w+7}.
//
// R1 restructure (latency theory): the old per-kk loop serialized
// {h-load -> keys-load -> dot -> 6-deep shfl chain} 8 times. Now:
//   Stage A: ALL 16 h dwordx4 loads issued back-to-back (max MLP; costs no
//            extra VGPRs since the whole cache is live until phase 2 anyway).
//   Stage B: sigma as two int4 loads (wave-uniform).
//   Stage C: branchless keys gather (invalid id -> row 0, result cndmask'd
//            to -1e9) so the scheduler can pipeline all 16 keys loads.
//   Reduction: 8x3 intra-8-lane-group butterflies + 7-cndmask lane select +
//            3 cross-group butterflies = 27 cross-lane ops (was 48), with 8
//            independent interleavable chains.
// Invalid rows sum to 64*(-1e9) = -6.4e10 across lanes: softmax-equivalent to
// -1e9 (exp underflows to 0 vs valid logits; all-invalid case stays uniform).

constexpr int K  = 64;
constexpr int D  = 512;
constexpr int NA = 64;
#define NEG_INF (-1e9f)

__global__ __launch_bounds__(512, 4)
void bda_kernel(const float* __restrict__ h, const float* __restrict__ keys,
                const int* __restrict__ sigma, float* __restrict__ out) {
    const int b    = blockIdx.x;
    const int tid  = threadIdx.x;
    const int w    = tid >> 6;    // wave 0..7
    const int lane = tid & 63;

    __shared__ float lg[K];                       // logits
    __shared__ __align__(16) float obuf[8 * D];   // per-wave partial outputs

    const float* hb = h + (size_t)b * (K * D);

    // ---- Stage A: issue ALL h loads up-front (16 independent dwordx4) ------
    float4 h0[8], h1[8];   // register cache of h[b, 8w+kk, lane*8 .. lane*8+8)
#pragma unroll
    for (int kk = 0; kk < 8; ++kk) {
        const float* hrow = hb + ((w << 3) + kk) * D + (lane << 3);
        h0[kk] = ((const float4*)hrow)[0];
        h1[kk] = ((const float4*)hrow)[1];
    }

    // ---- Stage B: this wave's 8 sigma ids (two 16B wave-uniform loads) -----
    const int4* sp = (const int4*)(sigma + b * K + (w << 3));
    const int4 sA = sp[0];
    const int4 sB = sp[1];
    const int sgarr[8] = {sA.x, sA.y, sA.z, sA.w, sB.x, sB.y, sB.z, sB.w};

    // ---- Stage C: branchless per-row dot partials --------------------------
    float d[8];
#pragma unroll
    for (int kk = 0; kk < 8; ++kk) {
        const int  sg    = sgarr[kk];
        const bool valid = (sg < NA);
        const int  si    = valid ? sg : 0;         // safe gather (row 0 is hot)
        const float* krow = keys + si * D + (lane << 3);
        const float4 k0 = ((const float4*)krow)[0];
        const float4 k1 = ((const float4*)krow)[1];
        const float acc = h0[kk].x * k0.x + h0[kk].y * k0.y
                        + h0[kk].z * k0.z + h0[kk].w * k0.w
                        + h1[kk].x * k1.x + h1[kk].y * k1.y
                        + h1[kk].z * k1.z + h1[kk].w * k1.w;
        d[kk] = valid ? acc : NEG_INF;   // invalid row: all 64 lanes -1e9
    }

    // ---- Grouped reduction: intra-8-lane-group sums (8 rows x 3 steps) -----
#pragma unroll
    for (int kk = 0; kk < 8; ++kk) {
        d[kk] += __shfl_xor(d[kk], 1, 64);
        d[kk] += __shfl_xor(d[kk], 2, 64);
        d[kk] += __shfl_xor(d[kk], 4, 64);
    }
    // lane l picks row (l&7)'s partial of its 8-lane group (7 cndmask tree)
    const float s0 = (lane & 1) ? d[1] : d[0];
    const float s1 = (lane & 1) ? d[3] : d[2];
    const float s2 = (lane & 1) ? d[5] : d[4];
    const float s3 = (lane & 1) ? d[7] : d[6];
    const float t0 = (lane & 2) ? s1 : s0;
    const float t1 = (lane & 2) ? s3 : s2;
    float v        = (lane & 4) ? t1 : t0;
    // cross-group sum: after these, lane l holds the full sum of row (l&7)
    v += __shfl_xor(v, 8, 64);
    v += __shfl_xor(v, 16, 64);
    v += __shfl_xor(v, 32, 64);
    if (lane < 8) lg[(w << 3) + lane] = v;
    __syncthreads();

    // ---- Softmax stats: butterfly over the 64 logits (each wave redundant) --
    const float vl = lg[lane];
    float m = vl;
#pragma unroll
    for (int off = 32; off > 0; off >>= 1)
        m = fmaxf(m, __shfl_xor(m, off, 64));
    float s = __expf(vl - m);
#pragma unroll
    for (int off = 32; off > 0; off >>= 1)
        s += __shfl_xor(s, off, 64);
    const float inv_s = 1.0f / s;
    // All-unassigned row: every logit equals the same -6.4e10, exp(0)=1,
    // alpha = 1/64 — identical to the reference's softmax of all -1e9.

    // ---- Phase 2: weighted pooling from the register cache ------------------
    float4 a0 = make_float4(0.f, 0.f, 0.f, 0.f);
    float4 a1 = make_float4(0.f, 0.f, 0.f, 0.f);
#pragma unroll
    for (int kk = 0; kk < 8; ++kk) {
        const float al = __expf(lg[(w << 3) + kk] - m) * inv_s;  // LDS broadcast
        a0.x += al * h0[kk].x;  a0.y += al * h0[kk].y;
        a0.z += al * h0[kk].z;  a0.w += al * h0[kk].w;
        a1.x += al * h1[kk].x;  a1.y += al * h1[kk].y;
        a1.z += al * h1[kk].z;  a1.w += al * h1[kk].w;
    }
    float* ob = obuf + w * D + (lane << 3);
    ((float4*)ob)[0] = a0;
    ((float4*)ob)[1] = a1;
    __syncthreads();

    // ---- Cross-wave reduce + coalesced store --------------------------------
    float r = 0.f;
#pragma unroll
    for (int w2 = 0; w2 < 8; ++w2)
        r += obuf[w2 * D + tid];          // stride-1 across lanes: conflict-free
    out[(size_t)b * D + tid] = r;
}

extern "C" void kernel_launch(void* const* d_in, const int* in_sizes, int n_in,
                              void* d_out, int out_size, void* d_ws, size_t ws_size,
                              hipStream_t stream) {
    const float* h     = (const float*)d_in[0];
    const float* keys  = (const float*)d_in[1];
    const int*   sigma = (const int*)d_in[2];
    float*       out   = (float*)d_out;
    const int B = in_sizes[2] / K;   // sigma has B*K elements
    bda_kernel<<<dim3(B), dim3(512), 0, stream>>>(h, keys, sigma, out);
}

// Round 2
// 668.950 us; speedup vs baseline: 1.0146x; 1.0146x over previous
//
#include <hip/hip_runtime.h>

// BlockDiagonalAggregator: out[b,:] = sum_k softmax_k(<keys[sigma[b,k]], h[b,k,:]>) * h[b,k,:]
// B=4096, K=64, D=512, N_AGENTS=64 (sigma==64 -> unassigned -> logit=-1e9)
//
// One block (512 threads = 8 waves) per batch row b. h[b] (128 KiB) read from
// HBM once into registers (64 f32/thread).
//
// R2: CONTIGUOUS-LANE LAYOUT. Previously lane l owned dims [8l,8l+8): each
// dwordx4 had a 32-B lane stride -> touched 32 half-used 64-B lines. Now lane
// l owns dims [4l,4l+4) and [256+4l,256+4l+4): every global_load_dwordx4 is a
// perfect 1 KiB contiguous burst (16 fully-used lines). Same for keys loads.
// Dot products sum over all lanes, so lane->dim ownership is free to choose;
// only the obuf write mapping changes (still conflict-free b128 writes).

constexpr int K  = 64;
constexpr int D  = 512;
constexpr int NA = 64;
#define NEG_INF (-1e9f)

__global__ __launch_bounds__(512, 4)
void bda_kernel(const float* __restrict__ h, const float* __restrict__ keys,
                const int* __restrict__ sigma, float* __restrict__ out) {
    const int b    = blockIdx.x;
    const int tid  = threadIdx.x;
    const int w    = tid >> 6;    // wave 0..7
    const int lane = tid & 63;

    __shared__ float lg[K];                       // logits
    __shared__ __align__(16) float obuf[8 * D];   // per-wave partial outputs

    const float* hb = h + (size_t)b * (K * D);
    const int    c0 = lane << 2;        // dims [4l, 4l+4)
    const int    c1 = 256 + (lane << 2);// dims [256+4l, 256+4l+4)

    // ---- sigma first: keys addresses resolve as early as possible ----------
    const int4* sp = (const int4*)(sigma + b * K + (w << 3));
    const int4 sA = sp[0];
    const int4 sB = sp[1];
    const int sgarr[8] = {sA.x, sA.y, sA.z, sA.w, sB.x, sB.y, sB.z, sB.w};

    // ---- h loads: 16 contiguous 1-KiB bursts per wave ----------------------
    float4 h0[8], h1[8];   // h[b, 8w+kk, c0..c0+4) and [c1..c1+4)
#pragma unroll
    for (int kk = 0; kk < 8; ++kk) {
        const float* hrow = hb + ((w << 3) + kk) * D;
        h0[kk] = *(const float4*)(hrow + c0);
        h1[kk] = *(const float4*)(hrow + c1);
    }

    // ---- branchless keys gather + per-row dot partials ---------------------
    float d[8];
#pragma unroll
    for (int kk = 0; kk < 8; ++kk) {
        const int  sg    = sgarr[kk];
        const bool valid = (sg < NA);
        const int  si    = valid ? sg : 0;         // safe gather (row 0 hot)
        const float* krow = keys + si * D;
        const float4 k0 = *(const float4*)(krow + c0);
        const float4 k1 = *(const float4*)(krow + c1);
        const float acc = h0[kk].x * k0.x + h0[kk].y * k0.y
                        + h0[kk].z * k0.z + h0[kk].w * k0.w
                        + h1[kk].x * k1.x + h1[kk].y * k1.y
                        + h1[kk].z * k1.z + h1[kk].w * k1.w;
        d[kk] = valid ? acc : NEG_INF;   // invalid row: all 64 lanes -1e9
    }

    // ---- grouped reduction: 8x3 intra-8-lane butterflies + select + 3 ------
#pragma unroll
    for (int kk = 0; kk < 8; ++kk) {
        d[kk] += __shfl_xor(d[kk], 1, 64);
        d[kk] += __shfl_xor(d[kk], 2, 64);
        d[kk] += __shfl_xor(d[kk], 4, 64);
    }
    const float s0 = (lane & 1) ? d[1] : d[0];
    const float s1 = (lane & 1) ? d[3] : d[2];
    const float s2 = (lane & 1) ? d[5] : d[4];
    const float s3 = (lane & 1) ? d[7] : d[6];
    const float t0 = (lane & 2) ? s1 : s0;
    const float t1 = (lane & 2) ? s3 : s2;
    float v        = (lane & 4) ? t1 : t0;
    v += __shfl_xor(v, 8, 64);
    v += __shfl_xor(v, 16, 64);
    v += __shfl_xor(v, 32, 64);
    if (lane < 8) lg[(w << 3) + lane] = v;   // lane l holds row (l&7)'s sum
    __syncthreads();

    // ---- softmax stats (redundant per wave, butterfly over 64 logits) ------
    const float vl = lg[lane];
    float m = vl;
#pragma unroll
    for (int off = 32; off > 0; off >>= 1)
        m = fmaxf(m, __shfl_xor(m, off, 64));
    float s = __expf(vl - m);
#pragma unroll
    for (int off = 32; off > 0; off >>= 1)
        s += __shfl_xor(s, off, 64);
    const float inv_s = 1.0f / s;
    // All-unassigned row: logits uniform (-6.4e10) -> alpha = 1/64, matching
    // the reference's softmax of all -1e9.

    // ---- weighted pooling from the register cache --------------------------
    float4 a0 = make_float4(0.f, 0.f, 0.f, 0.f);
    float4 a1 = make_float4(0.f, 0.f, 0.f, 0.f);
#pragma unroll
    for (int kk = 0; kk < 8; ++kk) {
        const float al = __expf(lg[(w << 3) + kk] - m) * inv_s;  // LDS broadcast
        a0.x += al * h0[kk].x;  a0.y += al * h0[kk].y;
        a0.z += al * h0[kk].z;  a0.w += al * h0[kk].w;
        a1.x += al * h1[kk].x;  a1.y += al * h1[kk].y;
        a1.z += al * h1[kk].z;  a1.w += al * h1[kk].w;
    }
    float* ob = obuf + w * D;
    *(float4*)(ob + c0) = a0;     // dims [4l,4l+4)      — contiguous b128
    *(float4*)(ob + c1) = a1;     // dims [256+4l,..+4)  — contiguous b128
    __syncthreads();

    // ---- cross-wave reduce + coalesced store -------------------------------
    float r = 0.f;
#pragma unroll
    for (int w2 = 0; w2 < 8; ++w2)
        r += obuf[w2 * D + tid];          // stride-1 across lanes: conflict-free
    out[(size_t)b * D + tid] = r;
}

extern "C" void kernel_launch(void* const* d_in, const int* in_sizes, int n_in,
                              void* d_out, int out_size, void* d_ws, size_t ws_size,
                              hipStream_t stream) {
    const float* h     = (const float*)d_in[0];
    const float* keys  = (const float*)d_in[1];
    const int*   sigma = (const int*)d_in[2];
    float*       out   = (float*)d_out;
    const int B = in_sizes[2] / K;   // sigma has B*K elements
    bda_kernel<<<dim3(B), dim3(512), 0, stream>>>(h, keys, sigma, out);
}